// Round 9
// baseline (176.165 us; speedup 1.0000x reference)
//
#include <hip/hip_runtime.h>

#define Bn 4
#define Tn 512
#define Mn 16
#define Dn 128
#define Pn 128
#define Hn 4
#define SCALE 0.08838834764831845f  // 1 / (2*sqrt(32))

typedef unsigned short u16;
typedef unsigned int u32;
typedef short s16;
typedef __attribute__((ext_vector_type(8))) s16 bf16x8;   // 8 bf16 = 4 VGPRs
typedef __attribute__((ext_vector_type(4))) float f32x4;  // MFMA C/D

__device__ __forceinline__ u16 f2b(float f) {  // fp32 -> bf16 rne
  u32 x; __builtin_memcpy(&x, &f, 4);
  x += 0x7fffu + ((x >> 16) & 1u);
  return (u16)(x >> 16);
}
__device__ __forceinline__ u32 pack2(float a, float b) {
  return (u32)f2b(a) | ((u32)f2b(b) << 16);
}
__device__ __forceinline__ bf16x8 ld8(const u16* p) {  // 16B frag load
  bf16x8 r; __builtin_memcpy(&r, p, 16); return r;
}
__device__ __forceinline__ void st8(u16* p, bf16x8 v) {  // 16B store
  __builtin_memcpy(p, &v, 16);
}
// fp32 -> bf16 fragment load: 8 consecutive floats, packed in-register.
// Same f2b RNE as the old cvt pass => bit-identical fragments.
__device__ __forceinline__ bf16x8 ldcvt8(const float* p) {
  const float4 a = *(const float4*)p;
  const float4 b = *(const float4*)(p + 4);
  bf16x8 r; u32* r32 = (u32*)&r;
  r32[0] = pack2(a.x, a.y); r32[1] = pack2(a.z, a.w);
  r32[2] = pack2(b.x, b.y); r32[3] = pack2(b.z, b.w);
  return r;
}
__device__ __forceinline__ f32x4 mfma16(bf16x8 a, bf16x8 b, f32x4 c) {
  // Verified mapping (rounds 2-4,7,8): D row (quad*4+reg) = a's l16-index,
  // D col (lane&15) = b's l16-index, k = kc*32 + quad*8 in both gathers.
  return __builtin_amdgcn_mfma_f32_16x16x32_bf16(a, b, c, 0, 0, 0);
}
#define ZERO4 ((f32x4){0.f, 0.f, 0.f, 0.f})

// --------------------------------------------------- projection (fused cvt) --
// Wave-autonomous, no barriers. Wave = (tsel, m, 32-row group); 5120 waves in
// 1280 blocks. Fragments load fp32 DIRECT from the inputs with in-register
// f2b packing (kills the old cvt pass; L2 serves the 64x W-reuse / 3x X-reuse).
// Stores: D-tiles round-trip a PRIVATE per-wave LDS slab (stride-40 rows),
// then 16B/lane stores, 4 lanes per 64B line (r8's write-amplification fix).
// Block 1280: lengths from mask (probed encoding; elem 0 always true).
__global__ __launch_bounds__(256, 2) void proj_fused(
    const float* __restrict__ inp, const float* __restrict__ pos,
    const float* __restrict__ Wq, const float* __restrict__ Wk,
    const float* __restrict__ Wv, const float* __restrict__ Wqt,
    const float* __restrict__ Wkt,
    const float* __restrict__ Bq, const float* __restrict__ Bk,
    const float* __restrict__ Bv, const float* __restrict__ Bqt,
    const float* __restrict__ Bkt, const void* __restrict__ mask,
    u16* __restrict__ Qa, u16* __restrict__ Ka, u16* __restrict__ Qb,
    u16* __restrict__ Kb, u16* __restrict__ Vt, int* __restrict__ lens) {
  const int tid = threadIdx.x;
  const int wv = tid >> 6, lane = tid & 63;

  if (blockIdx.x == 1280) {  // ---- lengths: wave wv handles batch wv ----
    const u32 w0 = ((const u32*)mask)[0];
    const int mode = (w0 == 1u) ? 0 : (w0 == 0x3F800000u) ? 1
                   : (w0 == 0x3F803F80u) ? 2 : 3;
    int c = 0;
    for (int t = lane; t < Tn; t += 64) {
      const size_t idx = ((size_t)wv * Tn + t) * Mn;
      int nz;
      if (mode == 0)      nz = (((const int*)mask)[idx] != 0);
      else if (mode == 1) nz = (((const u32*)mask)[idx] != 0u);
      else if (mode == 2) nz = (((const u16*)mask)[idx] != 0);
      else                nz = (((const unsigned char*)mask)[idx] != 0);
      c += nz;
    }
    for (int o = 32; o; o >>= 1) c += __shfl_xor(c, o);
    if (lane == 0) lens[wv] = c;
    return;
  }

  __shared__ __align__(16) u16 slab_all[4][4][32][40];  // 40 KB

  const int quad = lane >> 4, l16 = lane & 15;
  const int wu = blockIdx.x * 4 + wv;      // 0..5119
  const int tsel = wu % 5;
  const int rest = wu / 5;                 // 0..1023
  const int m = rest & (Mn - 1);
  const int rg = rest >> 4;                // 0..63 (32-row group; never crosses b)
  const int bt0 = rg * 32;                 // global row (READS)
  const int tl = bt0 & (Tn - 1);           // local-t base (STORES)
  const int b = bt0 >> 9;
  const int bmh0 = (b * Mn + m) * Hn;
  u16 (*slab)[32][40] = slab_all[wv];

  const float* W = (tsel == 0) ? Wq : (tsel == 1) ? Wk : (tsel == 2) ? Wv
                 : (tsel == 3) ? Wqt : Wkt;
  const float* Bb = (tsel == 0) ? Bq : (tsel == 1) ? Bk : (tsel == 2) ? Bv
                  : (tsel == 3) ? Bqt : Bkt;
  W += (size_t)m * Pn * Dn;
  const float* bias = Bb + m * Pn;
  const int usepos = (tsel >= 3);

  f32x4 acc[2][8];
#pragma unroll
  for (int tt = 0; tt < 2; ++tt)
#pragma unroll
    for (int n = 0; n < 8; ++n) acc[tt][n] = ZERO4;

#pragma unroll
  for (int kc = 0; kc < 4; ++kc) {
    const int ko = kc * 32 + quad * 8;
    bf16x8 x0, x1;
    if (usepos) {
      x0 = ldcvt8(pos + (size_t)(bt0 + l16) * Dn + ko);
      x1 = ldcvt8(pos + (size_t)(bt0 + 16 + l16) * Dn + ko);
    } else {
      x0 = ldcvt8(inp + ((size_t)(bt0 + l16) * Mn + m) * Dn + ko);
      x1 = ldcvt8(inp + ((size_t)(bt0 + 16 + l16) * Mn + m) * Dn + ko);
    }
#pragma unroll
    for (int n = 0; n < 8; ++n) {
      const bf16x8 w = ldcvt8(W + (size_t)(n * 16 + l16) * Dn + ko);
      acc[0][n] = mfma16(x0, w, acc[0][n]);
      acc[1][n] = mfma16(x1, w, acc[1][n]);
    }
  }

  if (tsel == 2) {
    // V: transposed tiles [e][t] -> Vt[bmh][e][t], packed 8B ds writes
#pragma unroll
    for (int n = 0; n < 8; ++n) {
      const int np = n >> 1;               // = h
      const int e_loc = (n & 1) * 16 + l16;
      const float bv = bias[n * 16 + l16];
#pragma unroll
      for (int tt = 0; tt < 2; ++tt) {
        const int t_loc = tt * 16 + quad * 4;
        uint2 d;
        d.x = pack2(acc[tt][n][0] + bv, acc[tt][n][1] + bv);
        d.y = pack2(acc[tt][n][2] + bv, acc[tt][n][3] + bv);
        *(uint2*)&slab[np][e_loc][t_loc] = d;
      }
    }
#pragma unroll
    for (int np = 0; np < 4; ++np)
#pragma unroll
      for (int i = 0; i < 2; ++i) {
        const int c = i * 64 + lane;
        const int e_loc = c >> 2, sub = c & 3;   // 4 lanes per 64B line
        const bf16x8 v = ld8(&slab[np][e_loc][sub * 8]);
        st8(Vt + ((size_t)(bmh0 + np) * 32 + e_loc) * Tn + tl + sub * 8, v);
      }
  } else {
    u16* dst = (tsel == 0) ? Qa : (tsel == 1) ? Ka : (tsel == 3) ? Qb : Kb;
    const float sc = (tsel == 0 || tsel == 3) ? SCALE : 1.f;
    // Q/K: [t][e] tiles -> dst[bmh][t][32]
#pragma unroll
    for (int n = 0; n < 8; ++n) {
      const int np = n >> 1;               // = h
      const int e = (n & 1) * 16 + l16;
      const float bv = bias[n * 16 + l16];
#pragma unroll
      for (int tt = 0; tt < 2; ++tt)
#pragma unroll
        for (int reg = 0; reg < 4; ++reg) {
          const int t_loc = tt * 16 + quad * 4 + reg;
          slab[np][t_loc][e] = f2b((acc[tt][n][reg] + bv) * sc);
        }
    }
#pragma unroll
    for (int np = 0; np < 4; ++np)
#pragma unroll
      for (int i = 0; i < 2; ++i) {
        const int c = i * 64 + lane;
        const int t_loc = c >> 2, sub = c & 3;   // 4 lanes per 64B line
        const bf16x8 v = ld8(&slab[np][t_loc][sub * 8]);
        st8(dst + ((size_t)(bmh0 + np) * Tn + tl + t_loc) * 32 + sub * 8, v);
      }
  }
}

// ------------------------------------------------------- attention (flash) ---
// Round-4/7/8 core (passing) + wave-uniform causal fast path: a 64-key chunk
// is fully valid iff s0+63 <= q0 (min q in wave) and s0+63 < len — skip the
// 64 cmp+cndmask in that case (bit-identical: mask was all-true there).
__global__ __launch_bounds__(256, 4) void attn_flash(
    const u16* __restrict__ Qa, const u16* __restrict__ Ka,
    const u16* __restrict__ Qb, const u16* __restrict__ Kb,
    const u16* __restrict__ Vt, const int* __restrict__ lens,
    float* __restrict__ out) {
  __shared__ __align__(16) u16 Ps[4 * 32 * 72];  // 18.4KB, per-wave slabs

  const int tid = threadIdx.x;
  const int wv = tid >> 6, lane = tid & 63;
  const int quad = lane >> 4, l16 = lane & 15;

  const int wu = blockIdx.x * 4 + wv;      // 0..4095
  const int qt = wu & 15;
  const int bmh = wu >> 4;
  const int b = bmh >> 6;                  // Mn*Hn = 64
  const int len = lens[b];
  const int q0 = qt * 32;

  const size_t rowbase = (size_t)bmh * Tn;
  const size_t vbase = (size_t)bmh * 32 * Tn;
  u16* myPs = &Ps[wv * 32 * 72];

  bf16x8 qf[2][2];
#pragma unroll
  for (int qs = 0; qs < 2; ++qs) {
    const size_t r = (rowbase + q0 + qs * 16 + l16) * 32 + quad * 8;
    qf[qs][0] = ld8(Qa + r);
    qf[qs][1] = ld8(Qb + r);
  }

  f32x4 O[2][2];  // [qs][es], D rows = e (quad*4+reg), cols = q (l16)
#pragma unroll
  for (int qs = 0; qs < 2; ++qs)
#pragma unroll
    for (int es = 0; es < 2; ++es) O[qs][es] = ZERO4;
  float mrow[2] = {-1e30f, -1e30f}, lsum[2] = {0.f, 0.f};

  const int s_hi = min(q0 + 32, len);      // len >= T/2 >= 1
  for (int s0 = 0; s0 < s_hi; s0 += 64) {
    f32x4 S[2][4];
#pragma unroll
    for (int st = 0; st < 4; ++st) {
      const size_t kr = (rowbase + s0 + st * 16 + l16) * 32 + quad * 8;
      const bf16x8 k0 = ld8(Ka + kr);
      const bf16x8 k1 = ld8(Kb + kr);
#pragma unroll
      for (int qs = 0; qs < 2; ++qs)
        S[qs][st] = mfma16(k1, qf[qs][1], mfma16(k0, qf[qs][0], ZERO4));
    }

    const bool full = (s0 + 63 <= q0) && (s0 + 63 < len);  // wave-uniform

#pragma unroll
    for (int qs = 0; qs < 2; ++qs) {
      if (!full) {
        const int q = q0 + qs * 16 + l16;
        const int qcap = min(q, len - 1);  // valid <=> s <= qcap
        const int sb = s0 + quad * 4;
#pragma unroll
        for (int st = 0; st < 4; ++st)
#pragma unroll
          for (int reg = 0; reg < 4; ++reg) {
            const int s = sb + st * 16 + reg;
            S[qs][st][reg] = (s <= qcap) ? S[qs][st][reg] : -1e30f;
          }
      }
      float cmax = -1e30f;
#pragma unroll
      for (int st = 0; st < 4; ++st)
#pragma unroll
        for (int reg = 0; reg < 4; ++reg) cmax = fmaxf(cmax, S[qs][st][reg]);
      cmax = fmaxf(cmax, __shfl_xor(cmax, 16));
      cmax = fmaxf(cmax, __shfl_xor(cmax, 32));
      const float mnew = fmaxf(mrow[qs], cmax);   // finite: >=1 valid key/chunk
      const float alpha = __expf(mrow[qs] - mnew);
      mrow[qs] = mnew;
      float rsum = 0.f;
      u32 pk[4][2];
#pragma unroll
      for (int st = 0; st < 4; ++st) {
        const float p0 = __expf(S[qs][st][0] - mnew);
        const float p1 = __expf(S[qs][st][1] - mnew);
        const float p2 = __expf(S[qs][st][2] - mnew);
        const float p3 = __expf(S[qs][st][3] - mnew);
        rsum += (p0 + p1) + (p2 + p3);
        pk[st][0] = pack2(p0, p1);
        pk[st][1] = pack2(p2, p3);
      }
      rsum += __shfl_xor(rsum, 16);
      rsum += __shfl_xor(rsum, 32);
      lsum[qs] = lsum[qs] * alpha + rsum;
#pragma unroll
      for (int es = 0; es < 2; ++es)
#pragma unroll
        for (int reg = 0; reg < 4; ++reg) O[qs][es][reg] *= alpha;
#pragma unroll
      for (int st = 0; st < 4; ++st) {
        uint2 d; d.x = pk[st][0]; d.y = pk[st][1];
        *(uint2*)&myPs[(qs * 16 + l16) * 72 + st * 16 + quad * 4] = d;
      }
    }

    // O^T += V^T . P
#pragma unroll
    for (int kc = 0; kc < 2; ++kc) {
      const int ko = kc * 32 + quad * 8;
      const bf16x8 pf0 = ld8(&myPs[l16 * 72 + ko]);
      const bf16x8 pf1 = ld8(&myPs[(16 + l16) * 72 + ko]);
      const bf16x8 vf0 = ld8(Vt + vbase + (size_t)l16 * Tn + s0 + ko);
      const bf16x8 vf1 = ld8(Vt + vbase + (size_t)(16 + l16) * Tn + s0 + ko);
      O[0][0] = mfma16(vf0, pf0, O[0][0]);
      O[0][1] = mfma16(vf1, pf0, O[0][1]);
      O[1][0] = mfma16(vf0, pf1, O[1][0]);
      O[1][1] = mfma16(vf1, pf1, O[1][1]);
    }
  }

  const int mm = (bmh >> 2) & (Mn - 1);
  const int h = bmh & (Hn - 1);
#pragma unroll
  for (int qs = 0; qs < 2; ++qs) {
    const float linv = 1.0f / lsum[qs];
    const int t = q0 + qs * 16 + l16;
    const size_t ob = (((size_t)b * Tn + t) * Mn + mm) * Pn + h * 32 + quad * 4;
#pragma unroll
    for (int es = 0; es < 2; ++es) {
      float4 o;
      o.x = O[qs][es][0] * linv; o.y = O[qs][es][1] * linv;
      o.z = O[qs][es][2] * linv; o.w = O[qs][es][3] * linv;
      *(float4*)&out[ob + es * 16] = o;
    }
  }
}

// ------------------------------------------------------------------ launch ---
extern "C" void kernel_launch(void* const* d_in, const int* in_sizes, int n_in,
                              void* d_out, int out_size, void* d_ws, size_t ws_size,
                              hipStream_t stream) {
  const float* inp = (const float*)d_in[0];
  const float* pos = (const float*)d_in[1];
  const void* mask = d_in[2];
  const float* Wq  = (const float*)d_in[3];
  const float* Bq  = (const float*)d_in[4];
  const float* Wk  = (const float*)d_in[5];
  const float* Bk  = (const float*)d_in[6];
  const float* Wv  = (const float*)d_in[7];
  const float* Bv  = (const float*)d_in[8];
  const float* Wqt = (const float*)d_in[9];
  const float* Bqt = (const float*)d_in[10];
  const float* Wkt = (const float*)d_in[11];
  const float* Bkt = (const float*)d_in[12];
  float* out = (float*)d_out;

  const size_t nA = (size_t)Bn * Mn * Hn * Tn * 32;  // 4.19M elems per array
  u16* Qa = (u16*)d_ws;
  u16* Ka = Qa + nA;
  u16* Qb = Ka + nA;
  u16* Kb = Qb + nA;
  u16* Vt = Kb + nA;
  int* lens = (int*)(Vt + nA);

  proj_fused<<<1281, 256, 0, stream>>>(
      inp, pos, Wq, Wk, Wv, Wqt, Wkt, Bq, Bk, Bv, Bqt, Bkt, mask,
      Qa, Ka, Qb, Kb, Vt, lens);
  attn_flash<<<Bn * Mn * Hn * (Tn / 32) / 4, 256, 0, stream>>>(
      Qa, Ka, Qb, Kb, Vt, lens, out);
}